// Round 5
// baseline (103.976 us; speedup 1.0000x reference)
//
#include <hip/hip_runtime.h>
#include <hip/hip_bf16.h>

typedef __attribute__((ext_vector_type(8))) __bf16 bf16x8;
typedef __attribute__((ext_vector_type(4))) float f32x4;

static constexpr int BROWS = 65536;
static constexpr int SDIM  = 512;
static constexpr int CDIM  = 256;
static constexpr float SLOPE = 0.01f;
static constexpr float HLP = 0.9189385332046727f;  // 0.5*log(2*pi)

// ws bf16 layout: W1T [64][512], W2T [32][64], W3T [256][32]
static constexpr int W1T_OFF = 0;
static constexpr int W2T_OFF = 64 * 512;
static constexpr int W3T_OFF = 64 * 512 + 32 * 64;
static constexpr int WS_ELEMS = W3T_OFF + 256 * 32;   // 43008

__global__ __launch_bounds__(256) void prep_weights(
    const float* __restrict__ W1, const float* __restrict__ W2,
    const float* __restrict__ W3, __bf16* __restrict__ ws)
{
    int tid = blockIdx.x * 256 + threadIdx.x;
    if (tid < 64 * 512) {                       // W1 [512][64] -> W1T [64][512]
        int n = tid >> 9, k = tid & 511;
        ws[W1T_OFF + tid] = (__bf16)W1[k * 64 + n];
    } else if (tid < 64 * 512 + 32 * 64) {      // W2 [64][32] -> W2T [32][64]
        int t = tid - 64 * 512;
        int n = t >> 6, k = t & 63;
        ws[W2T_OFF + t] = (__bf16)W2[k * 32 + n];
    } else if (tid < WS_ELEMS) {                // W3 [32][256] -> W3T [256][32]
        int t = tid - (64 * 512 + 32 * 64);
        int n = t >> 5, k = t & 31;
        ws[W3T_OFF + t] = (__bf16)W3[k * 256 + n];
    }
}

// swizzled LDS element index: row stride 64 bf16 (128B), XOR row&7 into 16B-chunk bits
__device__ __forceinline__ int swz(int row, int elem) {
    return (row * 64 + elem) ^ ((row & 7) << 3);
}

__device__ __forceinline__ bf16x8 cvt8(f32x4 a, f32x4 b) {
    bf16x8 r = {(__bf16)a.x, (__bf16)a.y, (__bf16)a.z, (__bf16)a.w,
                (__bf16)b.x, (__bf16)b.y, (__bf16)b.z, (__bf16)b.w};
    return r;
}

static constexpr int MT_STRIDE = 68;   // floats; 272 B rows, 16B-aligned

// One wave (64 threads) per block, 16 batch rows per block.
// LDS time-sharing: h1 (2 KB) is fully consumed (layer-2 A-frag reads) before
// mt (4352 B, overlapping h1) is first written in the layer-3 epilogue.
// Same-wave DS ops execute in order; aliasing through one char array keeps the
// compiler from reordering across the reuse boundary.
__global__ __launch_bounds__(64, 6) void policy_fused(
    const float* __restrict__ state, const float* __restrict__ b1,
    const float* __restrict__ b2, const float* __restrict__ b3,
    const float* __restrict__ noise, const __bf16* __restrict__ ws,
    float* __restrict__ actions, float* __restrict__ logp)
{
    __shared__ __align__(16) char ldsbuf[4352 + 2048];   // 6.25 KB/block
    __bf16* h1 = (__bf16*)ldsbuf;              // [16][64] bf16 (swz), dies after layer 2
    float*  mt = (float*)ldsbuf;               // [16][68] f32, reuses h1's space
    __bf16* h2 = (__bf16*)(ldsbuf + 4352);     // [16][64] bf16 (swz), cols 0..31 used

    const int lane = threadIdx.x & 63;
    const int lr   = lane & 15;   // A-row / B-col index
    const int lq   = lane >> 4;   // k-chunk / C-row-quad index

    const int rowbase = blockIdx.x * 16;   // this block's 16 rows

    const __bf16* W1T = ws + W1T_OFF;
    const __bf16* W2T = ws + W2T_OFF;
    const __bf16* W3T = ws + W3T_OFF;

    const f32x4 zero4 = {0.f, 0.f, 0.f, 0.f};

    // preload tiny biases (L1/L2-hot)
    float bv1[4], bv2[2];
    #pragma unroll
    for (int n = 0; n < 4; ++n) bv1[n] = b1[n * 16 + lr];
    #pragma unroll
    for (int n = 0; n < 2; ++n) bv2[n] = b2[n * 16 + lr];

    // ---------------- layer 1: [16 rows] x [64 cols], K=512 ----------------
    f32x4 acc[4] = {zero4, zero4, zero4, zero4};
    const float* sp = state + (size_t)(rowbase + lr) * SDIM + lq * 8;
    const __bf16* wbase = W1T + lr * SDIM + lq * 8;
    #pragma unroll 4
    for (int k0 = 0; k0 < SDIM; k0 += 32) {
        f32x4 sa = *(const f32x4*)(sp + k0);
        f32x4 sb = *(const f32x4*)(sp + k0 + 4);
        bf16x8 a = cvt8(sa, sb);
        #pragma unroll
        for (int n = 0; n < 4; ++n) {
            bf16x8 b = *(const bf16x8*)(wbase + k0 + n * 16 * SDIM);
            acc[n] = __builtin_amdgcn_mfma_f32_16x16x32_bf16(a, b, acc[n], 0, 0, 0);
        }
    }
    #pragma unroll
    for (int n = 0; n < 4; ++n) {
        #pragma unroll
        for (int r = 0; r < 4; ++r) {
            float v = acc[n][r] + bv1[n];
            v = (v >= 0.f) ? v : SLOPE * v;
            int row = lq * 4 + r;
            h1[swz(row, n * 16 + lr)] = (__bf16)v;
        }
    }
    // no __syncthreads(): single wave, same-wave DS ops are in-order

    // ---------------- layer 2: [16 rows] x [32 cols], K=64 ----------------
    f32x4 c2[2] = {zero4, zero4};
    #pragma unroll
    for (int kk = 0; kk < 2; ++kk) {
        bf16x8 a = *(const bf16x8*)&h1[swz(lr, kk * 32 + lq * 8)];
        #pragma unroll
        for (int n = 0; n < 2; ++n) {
            bf16x8 b = *(const bf16x8*)(W2T + (n * 16 + lr) * 64 + kk * 32 + lq * 8);
            c2[n] = __builtin_amdgcn_mfma_f32_16x16x32_bf16(a, b, c2[n], 0, 0, 0);
        }
    }
    #pragma unroll
    for (int n = 0; n < 2; ++n) {
        #pragma unroll
        for (int r = 0; r < 4; ++r) {
            float v = c2[n][r] + bv2[n];
            v = (v >= 0.f) ? v : SLOPE * v;
            int row = lq * 4 + r;
            h2[swz(row, n * 16 + lr)] = (__bf16)v;
        }
    }

    // ---------------- layer 3 + epilogue, 4 groups of 64 cols ----------------
    bf16x8 a3 = *(const bf16x8*)&h2[swz(lr, lq * 8)];
    const int row = lane >> 2;            // 0..15 (read-back row)
    const int q   = lane & 3;             // 16-col quarter within group
    const size_t gbase = (size_t)(rowbase + row) * CDIM;
    float lp = 0.f;

    f32x4 nbuf[2][4];
    bf16x8 w3f[2][4];
    #pragma unroll
    for (int j = 0; j < 4; ++j) {
        nbuf[0][j] = *(const f32x4*)(noise + gbase + q * 16 + j * 4);
        w3f[0][j]  = *(const bf16x8*)(W3T + (j * 16 + lr) * 32 + lq * 8);
    }

    #pragma unroll
    for (int g = 0; g < 4; ++g) {
        // prefetch next group's noise + W3T frags
        if (g < 3) {
            #pragma unroll
            for (int j = 0; j < 4; ++j) {
                nbuf[(g + 1) & 1][j] = *(const f32x4*)(noise + gbase + (g + 1) * 64 + q * 16 + j * 4);
                w3f[(g + 1) & 1][j]  = *(const bf16x8*)(W3T + ((g + 1) * 64 + j * 16 + lr) * 32 + lq * 8);
            }
        }
        f32x4 b3v[4];
        #pragma unroll
        for (int j = 0; j < 4; ++j)
            b3v[j] = *(const f32x4*)(b3 + g * 64 + q * 16 + j * 4);

        // MFMA phase: 4 col-tiles -> LDS transpose buffer
        #pragma unroll
        for (int t = 0; t < 4; ++t) {
            f32x4 c = __builtin_amdgcn_mfma_f32_16x16x32_bf16(a3, w3f[g & 1][t], zero4, 0, 0, 0);
            #pragma unroll
            for (int r = 0; r < 4; ++r)
                mt[(lq * 4 + r) * MT_STRIDE + t * 16 + lr] = c[r];
        }
        // read-back phase: vectorized noise/actions, faithful rounding for z
        #pragma unroll
        for (int j = 0; j < 4; ++j) {
            f32x4 m4 = *(const f32x4*)&mt[row * MT_STRIDE + q * 16 + j * 4];
            f32x4 mean = m4 + b3v[j];
            f32x4 av = mean + nbuf[g & 1][j];
            *(f32x4*)(actions + gbase + g * 64 + q * 16 + j * 4) = av;
            f32x4 zv = av - mean;          // replicate reference rounding exactly
            lp += -0.5f * (zv.x * zv.x + zv.y * zv.y + zv.z * zv.z + zv.w * zv.w) - 4.0f * HLP;
        }
    }
    // 4 lanes (q=0..3) share each row
    lp += __shfl_xor(lp, 1, 64);
    lp += __shfl_xor(lp, 2, 64);
    if (q == 0)
        logp[rowbase + row] = lp;
}

extern "C" void kernel_launch(void* const* d_in, const int* in_sizes, int n_in,
                              void* d_out, int out_size, void* d_ws, size_t ws_size,
                              hipStream_t stream)
{
    const float* state = (const float*)d_in[0];
    const float* W1    = (const float*)d_in[1];
    const float* b1    = (const float*)d_in[2];
    const float* W2    = (const float*)d_in[3];
    const float* b2    = (const float*)d_in[4];
    const float* W3    = (const float*)d_in[5];
    const float* b3    = (const float*)d_in[6];
    const float* noise = (const float*)d_in[7];

    if (ws_size < (size_t)WS_ELEMS * sizeof(__bf16)) return;  // need 86 KB scratch
    __bf16* ws = (__bf16*)d_ws;

    float* actions = (float*)d_out;
    float* logp    = actions + (size_t)BROWS * CDIM;

    prep_weights<<<(WS_ELEMS + 255) / 256, 256, 0, stream>>>(W1, W2, W3, ws);
    policy_fused<<<BROWS / 16, 64, 0, stream>>>(state, b1, b2, b3, noise, ws,
                                                actions, logp);
}

// Round 6
// 89.182 us; speedup vs baseline: 1.1659x; 1.1659x over previous
//
#include <hip/hip_runtime.h>
#include <hip/hip_bf16.h>

typedef __attribute__((ext_vector_type(8))) __bf16 bf16x8;
typedef __attribute__((ext_vector_type(4))) float f32x4;

static constexpr int BROWS = 65536;
static constexpr int SDIM  = 512;
static constexpr int CDIM  = 256;
static constexpr float SLOPE = 0.01f;
static constexpr float HLP = 0.9189385332046727f;  // 0.5*log(2*pi)

// ws bf16 layout: W1T [64][512], W2T [32][64], W3T [256][32]
static constexpr int W1T_OFF = 0;
static constexpr int W2T_OFF = 64 * 512;
static constexpr int W3T_OFF = 64 * 512 + 32 * 64;
static constexpr int WS_ELEMS = W3T_OFF + 256 * 32;   // 43008

__global__ __launch_bounds__(256) void prep_weights(
    const float* __restrict__ W1, const float* __restrict__ W2,
    const float* __restrict__ W3, __bf16* __restrict__ ws)
{
    int tid = blockIdx.x * 256 + threadIdx.x;
    if (tid < 64 * 512) {                       // W1 [512][64] -> W1T [64][512]
        int n = tid >> 9, k = tid & 511;
        ws[W1T_OFF + tid] = (__bf16)W1[k * 64 + n];
    } else if (tid < 64 * 512 + 32 * 64) {      // W2 [64][32] -> W2T [32][64]
        int t = tid - 64 * 512;
        int n = t >> 6, k = t & 63;
        ws[W2T_OFF + t] = (__bf16)W2[k * 32 + n];
    } else if (tid < WS_ELEMS) {                // W3 [32][256] -> W3T [256][32]
        int t = tid - (64 * 512 + 32 * 64);
        int n = t >> 5, k = t & 31;
        ws[W3T_OFF + t] = (__bf16)W3[k * 256 + n];
    }
}

// swizzled LDS element index for bf16 tiles: row stride 64 bf16 (128B)
__device__ __forceinline__ int swz(int row, int elem) {
    return (row * 64 + elem) ^ ((row & 7) << 3);
}

__device__ __forceinline__ bf16x8 cvt8(f32x4 a, f32x4 b) {
    bf16x8 r = {(__bf16)a.x, (__bf16)a.y, (__bf16)a.z, (__bf16)a.w,
                (__bf16)b.x, (__bf16)b.y, (__bf16)b.z, (__bf16)b.w};
    return r;
}

__device__ __forceinline__ f32x4 lrelu4(f32x4 v) {
    f32x4 r;
    r.x = (v.x >= 0.f) ? v.x : SLOPE * v.x;
    r.y = (v.y >= 0.f) ? v.y : SLOPE * v.y;
    r.z = (v.z >= 0.f) ? v.z : SLOPE * v.z;
    r.w = (v.w >= 0.f) ? v.w : SLOPE * v.w;
    return r;
}

static constexpr int PB_STRIDE = 68;   // floats; 272 B rows, 16B-aligned, odd 16B-chunk stride

// 4 waves/block = 2 pairs; each pair owns 16 batch rows, K-split 256/256 across
// the pair for layer 1. Per-wave 4352-B LDS buffer time-shared:
//   partial C (16x64 f32, stride 68)  ->  h2 (16x64 bf16 swz)  ->  mean-transpose (16x68 f32)
// 2048 blocks x 17.4 KB LDS x VGPR<=64  => 8 blocks/CU = 32 waves/CU (100%).
__global__ __launch_bounds__(256, 8) void policy_fused(
    const float* __restrict__ state, const float* __restrict__ b1,
    const float* __restrict__ b2, const float* __restrict__ b3,
    const float* __restrict__ noise, const __bf16* __restrict__ ws,
    float* __restrict__ actions, float* __restrict__ logp)
{
    __shared__ __align__(16) char ldsraw[4][4352];

    const int tid  = threadIdx.x;
    const int wave = tid >> 6;
    const int lane = tid & 63;
    const int wp   = wave & 1;    // wave-in-pair (K half / row half)
    const int pair = wave >> 1;   // 0,1
    const int lr   = lane & 15;   // A-row / B-col index
    const int lq   = lane >> 4;   // k-chunk / C-row-quad index

    const int rowbase = blockIdx.x * 32 + pair * 16;   // this pair's 16 rows

    const __bf16* W1T = ws + W1T_OFF;
    const __bf16* W2T = ws + W2T_OFF;
    const __bf16* W3T = ws + W3T_OFF;

    float*  mybuf = (float*)ldsraw[wave];
    float*  pb0   = (float*)ldsraw[pair * 2];
    float*  pb1   = (float*)ldsraw[pair * 2 + 1];
    __bf16* h2    = (__bf16*)ldsraw[wave];
    float*  mt    = (float*)ldsraw[wave];

    const f32x4 zero4 = {0.f, 0.f, 0.f, 0.f};

    // ---------- layer 1 partial: 16 rows x 64 cols, this wave's K half ----------
    f32x4 acc[4] = {zero4, zero4, zero4, zero4};
    const float*  sp    = state + (size_t)(rowbase + lr) * SDIM + wp * 256 + lq * 8;
    const __bf16* wbase = W1T + lr * SDIM + wp * 256 + lq * 8;
    #pragma unroll
    for (int k0 = 0; k0 < 256; k0 += 32) {
        f32x4 sa = *(const f32x4*)(sp + k0);
        f32x4 sb = *(const f32x4*)(sp + k0 + 4);
        bf16x8 a = cvt8(sa, sb);
        #pragma unroll
        for (int n = 0; n < 4; ++n) {
            bf16x8 b = *(const bf16x8*)(wbase + k0 + n * 16 * SDIM);
            acc[n] = __builtin_amdgcn_mfma_f32_16x16x32_bf16(a, b, acc[n], 0, 0, 0);
        }
    }
    // write partial C to my buffer: [row][col], stride 68 floats
    #pragma unroll
    for (int n = 0; n < 4; ++n)
        #pragma unroll
        for (int r = 0; r < 4; ++r)
            mybuf[(lq * 4 + r) * PB_STRIDE + n * 16 + lr] = acc[n][r];
    __syncthreads();

    // ---------- combine halves -> A-frags for layer 2 (bias+LReLU fused) ----------
    const int rb = lr * PB_STRIDE;
    f32x4 s0 = *(const f32x4*)&pb0[rb + lq * 8]      + *(const f32x4*)&pb1[rb + lq * 8];
    f32x4 s1 = *(const f32x4*)&pb0[rb + lq * 8 + 4]  + *(const f32x4*)&pb1[rb + lq * 8 + 4];
    f32x4 s2 = *(const f32x4*)&pb0[rb + 32 + lq * 8]     + *(const f32x4*)&pb1[rb + 32 + lq * 8];
    f32x4 s3 = *(const f32x4*)&pb0[rb + 32 + lq * 8 + 4] + *(const f32x4*)&pb1[rb + 32 + lq * 8 + 4];
    s0 = lrelu4(s0 + *(const f32x4*)(b1 + lq * 8));
    s1 = lrelu4(s1 + *(const f32x4*)(b1 + lq * 8 + 4));
    s2 = lrelu4(s2 + *(const f32x4*)(b1 + 32 + lq * 8));
    s3 = lrelu4(s3 + *(const f32x4*)(b1 + 32 + lq * 8 + 4));
    bf16x8 af0 = cvt8(s0, s1);   // h1 row lr, cols lq*8..+7
    bf16x8 af1 = cvt8(s2, s3);   // h1 row lr, cols 32+lq*8..+7

    // ---------- layer 2: 16 rows x 32 cols, K=64 (duplicated per pair, tiny) ----------
    f32x4 c2[2] = {zero4, zero4};
    #pragma unroll
    for (int n = 0; n < 2; ++n) {
        bf16x8 b0 = *(const bf16x8*)(W2T + (n * 16 + lr) * 64 + lq * 8);
        bf16x8 b1f = *(const bf16x8*)(W2T + (n * 16 + lr) * 64 + 32 + lq * 8);
        c2[n] = __builtin_amdgcn_mfma_f32_16x16x32_bf16(af0, b0, c2[n], 0, 0, 0);
        c2[n] = __builtin_amdgcn_mfma_f32_16x16x32_bf16(af1, b1f, c2[n], 0, 0, 0);
    }
    __syncthreads();   // partner must finish reading my partial buffer before h2 overwrite
    asm volatile("" ::: "memory");
    #pragma unroll
    for (int n = 0; n < 2; ++n) {
        float bv = b2[n * 16 + lr];
        #pragma unroll
        for (int r = 0; r < 4; ++r) {
            float v = c2[n][r] + bv;
            v = (v >= 0.f) ? v : SLOPE * v;
            h2[swz(lq * 4 + r, n * 16 + lr)] = (__bf16)v;
        }
    }
    bf16x8 a3f = *(const bf16x8*)&h2[swz(lr, lq * 8)];  // same-wave in-order DS
    asm volatile("" ::: "memory");

    // ---------- layer 3 + epilogue: all 4 col groups, this wave's 8 rows ----------
    const int row8 = lane >> 3;            // 0..7
    const int q8   = lane & 7;             // 8-col slot within group
    const int lrow = wp * 8 + row8;        // local row for read-back
    const int grow = rowbase + lrow;
    const size_t gb = (size_t)grow * CDIM;
    float lp = 0.f;

    #pragma unroll
    for (int g = 0; g < 4; ++g) {
        f32x4 n0 = *(const f32x4*)(noise + gb + g * 64 + q8 * 8);
        f32x4 n1 = *(const f32x4*)(noise + gb + g * 64 + q8 * 8 + 4);
        f32x4 bb0 = *(const f32x4*)(b3 + g * 64 + q8 * 8);
        f32x4 bb1 = *(const f32x4*)(b3 + g * 64 + q8 * 8 + 4);

        // MFMA phase: 4 col-tiles (all 16 rows, duplicated per pair) -> mt
        #pragma unroll
        for (int t = 0; t < 4; ++t) {
            bf16x8 bfrag = *(const bf16x8*)(W3T + (g * 64 + t * 16 + lr) * 32 + lq * 8);
            f32x4 c = __builtin_amdgcn_mfma_f32_16x16x32_bf16(a3f, bfrag, zero4, 0, 0, 0);
            #pragma unroll
            for (int r = 0; r < 4; ++r)
                mt[(lq * 4 + r) * PB_STRIDE + t * 16 + lr] = c[r];
        }
        // read-back: this wave's 8 rows, vectorized
        f32x4 m0 = *(const f32x4*)&mt[lrow * PB_STRIDE + q8 * 8];
        f32x4 m1 = *(const f32x4*)&mt[lrow * PB_STRIDE + q8 * 8 + 4];
        f32x4 mean0 = m0 + bb0, mean1 = m1 + bb1;
        f32x4 av0 = mean0 + n0, av1 = mean1 + n1;
        *(f32x4*)(actions + gb + g * 64 + q8 * 8)     = av0;
        *(f32x4*)(actions + gb + g * 64 + q8 * 8 + 4) = av1;
        f32x4 z0 = av0 - mean0, z1 = av1 - mean1;   // replicate reference rounding
        lp += -0.5f * (z0.x * z0.x + z0.y * z0.y + z0.z * z0.z + z0.w * z0.w +
                       z1.x * z1.x + z1.y * z1.y + z1.z * z1.z + z1.w * z1.w) - 8.0f * HLP;
    }
    // 8 lanes (q8) share each row
    lp += __shfl_xor(lp, 1, 64);
    lp += __shfl_xor(lp, 2, 64);
    lp += __shfl_xor(lp, 4, 64);
    if (q8 == 0)
        logp[grow] = lp;
}

extern "C" void kernel_launch(void* const* d_in, const int* in_sizes, int n_in,
                              void* d_out, int out_size, void* d_ws, size_t ws_size,
                              hipStream_t stream)
{
    const float* state = (const float*)d_in[0];
    const float* W1    = (const float*)d_in[1];
    const float* b1    = (const float*)d_in[2];
    const float* W2    = (const float*)d_in[3];
    const float* b2    = (const float*)d_in[4];
    const float* W3    = (const float*)d_in[5];
    const float* b3    = (const float*)d_in[6];
    const float* noise = (const float*)d_in[7];

    if (ws_size < (size_t)WS_ELEMS * sizeof(__bf16)) return;  // need 86 KB scratch
    __bf16* ws = (__bf16*)d_ws;

    float* actions = (float*)d_out;
    float* logp    = actions + (size_t)BROWS * CDIM;

    prep_weights<<<(WS_ELEMS + 255) / 256, 256, 0, stream>>>(W1, W2, W3, ws);
    policy_fused<<<BROWS / 32, 256, 0, stream>>>(state, b1, b2, b3, noise, ws,
                                                 actions, logp);
}